// Round 2
// baseline (379.906 us; speedup 1.0000x reference)
//
#include <hip/hip_runtime.h>
#include <cstddef>

#define B_ROWS 8192
#define DIM    1024
#define NSESS  32
#define MT     128       // rows per M-tile
#define NTILE  128       // cols per N-tile
#define BK     64        // fp32 per K-chunk per iter = 2 MFMA k-steps
#define KITERS (DIM / BK)   // 16
#define TPE    3         // m-tiles per expert (validated: max expert count <= 384)
#define LROW   72        // shorts per LDS row: 64 bf16 + 8 pad = 144 B (16B-mult)
#define TSZ    (MT * LROW)
#define NXCD   8
#define EPX    (NSESS / NXCD)        // experts per XCD = 4
#define BPE    (TPE * (DIM / NTILE)) // blocks per expert = 24

typedef __attribute__((ext_vector_type(8))) short short8;
typedef __attribute__((ext_vector_type(4))) float floatx4;
typedef __attribute__((ext_vector_type(4))) int intx4;
typedef __attribute__((ext_vector_type(2))) unsigned int uintx2;

// RNE fp32->bf16 for two values, packed into one dword via v_perm_b32.
__device__ __forceinline__ unsigned pack_bf16_2(float fa, float fb) {
  unsigned a = __builtin_bit_cast(unsigned, fa);
  unsigned b = __builtin_bit_cast(unsigned, fb);
  a += 0x7fffu + ((a >> 16) & 1u);
  b += 0x7fffu + ((b >> 16) & 1u);
  return __builtin_amdgcn_perm(b, a, 0x07060302u); // low = bf16(fa), high = bf16(fb)
}

// Round-7 structure (post-mortem r6: XCD remap halved FETCH_SIZE (206->90MB)
// but dur_us flat => NOT BW-bound. ~6.5k CU-cycles/phase vs ~1.5k of issued
// work; MfmaUtil*t and VALUBusy*t match issued-work estimates exactly =>
// latency-bound at 2 waves/SIMD (LDS-capped). Fix: trade the intra-block
// double buffer (which only covered ~160cy of MFMA) for inter-block overlap:
//  - SINGLE A/B LDS buffer: 38.4 KB/block -> 4 blocks/CU, 4 waves/SIMD
//  - phase: LOAD(next)->COMPUTE->bar->CVTWRITE->bar; per-wave vmcnt keeps
//    next-chunk loads in flight across compute+barrier
//  - B-tile k0 loads issued BEFORE the sidx scan (no row_ids dependency)
//  - keep: XCD-clustered remap, 16Bx16-lane row staging, bf16 LDS +16B pad,
//    direct ds_read_b128 fragments
__global__ __launch_bounds__(256, 4) void gemm_kernel(
    const float* __restrict__ x, const float* __restrict__ W,
    const float* __restrict__ bias, const int* __restrict__ sidx,
    float* __restrict__ out)
{
  __shared__ __align__(16) short As[TSZ], Bs[TSZ];
  __shared__ int row_ids[MT];
  __shared__ int psum[256];

  // ---- XCD-clustered decode ----
  const int hw    = blockIdx.x;          // 0..767, assumed XCD = hw % 8
  const int xcd   = hw & (NXCD - 1);
  const int r     = hw >> 3;             // 0..95: within-XCD sequence
  const int s     = xcd * EPX + (r / BPE);   // expert, clustered per XCD
  const int rr    = r % BPE;             // 0..23
  const int ntile = rr / TPE;            // 0..7 (W slice shared by 3 mtiles)
  const int mtile = rr % TPE;
  const int tid   = threadIdx.x;

  const int lane = tid & 63;
  const int wv   = tid >> 6;            // wave id
  const int wm   = wv >> 1;             // 0..1 : 64-row half
  const int wn   = wv & 1;              // 0..1 : 64-col half
  const int fr   = lane & 15;           // fragment row within 16
  const int kg   = lane >> 4;           // fragment k-group (k = kg*8 + j)

  // ---- staging geometry: instr j covers tile-rows srow+j*4, 256 B each ----
  const int srow   = wv * 32 + (lane >> 4);
  const int schunk = lane & 15;

  // B pointers + k0 B-loads issued immediately (hide under the sidx scan).
  const float* bpt[8];
  floatx4 wreg[8];
#pragma unroll
  for (int j = 0; j < 8; ++j) {
    const int tr = srow + j * 4;
    bpt[j] = W + (size_t)s * DIM * DIM + (size_t)(ntile * NTILE + tr) * DIM + schunk * 4;
    wreg[j] = *(const floatx4*)bpt[j];
  }

  // ---- ranked compaction: rows with sidx==s, ranks [mtile*128, +128) ----
  const intx4* sv = (const intx4*)(sidx + tid * 32);
  int c = 0;
#pragma unroll
  for (int j = 0; j < 8; ++j) {
    const intx4 v = sv[j];
#pragma unroll
    for (int e = 0; e < 4; ++e) c += (v[e] == s);
  }
  psum[tid] = c;
  __syncthreads();
#pragma unroll
  for (int d = 1; d < 256; d <<= 1) {
    const int mine = psum[tid];
    const int add  = (tid >= d) ? psum[tid - d] : 0;
    __syncthreads();
    psum[tid] = mine + add;
    __syncthreads();
  }
  const int total = psum[255];
  const int nrows = (total - mtile * MT) < 0 ? 0
                  : ((total - mtile * MT) > MT ? MT : (total - mtile * MT));
  if (nrows == 0) return;               // uniform across block
  const int base_rank = psum[tid] - c;

  if (tid < MT) row_ids[tid] = -1;
  __syncthreads();
  {
    int r2 = base_rank;
    const int lo = mtile * MT, hi = lo + MT;
#pragma unroll
    for (int j = 0; j < 8; ++j) {
      const intx4 v = sv[j];
#pragma unroll
      for (int e = 0; e < 4; ++e) {
        if (v[e] == s) {
          if (r2 >= lo && r2 < hi) row_ids[r2 - lo] = tid * 32 + 4 * j + e;
          ++r2;
        }
      }
    }
  }
  __syncthreads();

  const float* apt[8];
  floatx4 xreg[8];
#pragma unroll
  for (int j = 0; j < 8; ++j) {
    const int tr = srow + j * 4;
    int ar = row_ids[tr];
    if (ar < 0) ar = 0;                 // finite dummy; epilogue masks rows >= nrows
    apt[j] = x + (size_t)ar * DIM + schunk * 4;
    xreg[j] = *(const floatx4*)apt[j];  // k0 A-loads
  }

  floatx4 acc[4][4] = {};

#define LOADREGS(KB)                                                           \
  {                                                                            \
    _Pragma("unroll")                                                          \
    for (int j = 0; j < 8; ++j) {                                              \
      xreg[j] = *(const floatx4*)(apt[j] + (KB) * BK);                         \
      wreg[j] = *(const floatx4*)(bpt[j] + (KB) * BK);                         \
    }                                                                          \
  }

#define CVTWRITE()                                                             \
  {                                                                            \
    _Pragma("unroll")                                                          \
    for (int j = 0; j < 8; ++j) {                                              \
      const int off = (srow + j * 4) * LROW + schunk * 4;                      \
      uintx2 ua = { pack_bf16_2(xreg[j][0], xreg[j][1]),                       \
                    pack_bf16_2(xreg[j][2], xreg[j][3]) };                     \
      uintx2 ub = { pack_bf16_2(wreg[j][0], wreg[j][1]),                       \
                    pack_bf16_2(wreg[j][2], wreg[j][3]) };                     \
      *(uintx2*)&As[off] = ua;                                                 \
      *(uintx2*)&Bs[off] = ub;                                                 \
    }                                                                          \
  }

#define COMPUTE()                                                              \
  {                                                                            \
    _Pragma("unroll")                                                          \
    for (int s2 = 0; s2 < 2; ++s2) {                                           \
      short8 fa[4], fb[4];                                                     \
      _Pragma("unroll")                                                        \
      for (int i = 0; i < 4; ++i) {                                            \
        fa[i] = *(const short8*)&As[(wm * 64 + i * 16 + fr) * LROW + s2 * 32 + kg * 8]; \
        fb[i] = *(const short8*)&Bs[(wn * 64 + i * 16 + fr) * LROW + s2 * 32 + kg * 8]; \
      }                                                                        \
      _Pragma("unroll")                                                        \
      for (int mi = 0; mi < 4; ++mi)                                           \
        _Pragma("unroll")                                                      \
        for (int ni = 0; ni < 4; ++ni)                                         \
          acc[mi][ni] = __builtin_amdgcn_mfma_f32_16x16x32_bf16(               \
              fa[mi], fb[ni], acc[mi][ni], 0, 0, 0);                           \
    }                                                                          \
  }

  // prologue: k0 already in regs -> stage into LDS
  CVTWRITE();
  __syncthreads();

  for (int kb = 0; kb < KITERS; ++kb) {
    if (kb + 1 < KITERS) LOADREGS(kb + 1);   // in flight across compute+barrier
    COMPUTE();
    if (kb + 1 < KITERS) {
      __syncthreads();                       // all waves done reading LDS
      CVTWRITE();                            // vmcnt wait lands here
      __syncthreads();                       // writes visible
    }
  }

#undef LOADREGS
#undef CVTWRITE
#undef COMPUTE

  // epilogue: D row = (lane>>4)*4 + reg, D col = lane&15
  const int col0 = ntile * NTILE + wn * 64;
#pragma unroll
  for (int ni = 0; ni < 4; ++ni) {
    const int n = col0 + ni * 16 + fr;
    const float bv = bias[s * DIM + n];
#pragma unroll
    for (int mi = 0; mi < 4; ++mi) {
      const int mbase = wm * 64 + mi * 16 + kg * 4;
#pragma unroll
      for (int rr2 = 0; rr2 < 4; ++rr2) {
        const int ml = mbase + rr2;
        if (ml < nrows) {
          const int orow = row_ids[ml];
          out[(size_t)orow * DIM + n] = acc[mi][ni][rr2] + bv;
        }
      }
    }
  }
}

extern "C" void kernel_launch(void* const* d_in, const int* in_sizes, int n_in,
                              void* d_out, int out_size, void* d_ws, size_t ws_size,
                              hipStream_t stream) {
  const float* x    = (const float*)d_in[0];
  const float* W    = (const float*)d_in[1];
  const float* b    = (const float*)d_in[2];
  const int*   sidx = (const int*)d_in[3];
  float* out = (float*)d_out;
  (void)d_ws; (void)ws_size;  // deliberately unused (round-1 post-mortem)

  hipLaunchKernelGGL(gemm_kernel, dim3(NSESS * TPE * (DIM / NTILE)), dim3(256), 0, stream,
                     x, W, b, sidx, out);
}

// Round 3
// 280.533 us; speedup vs baseline: 1.3542x; 1.3542x over previous
//
#include <hip/hip_runtime.h>
#include <cstddef>

#define B_ROWS 8192
#define DIM    1024
#define NSESS  32
#define MT     128       // rows per M-tile
#define NTILE  128       // cols per N-tile
#define BK     64        // fp32 per K-chunk per iter = 2 MFMA k-steps
#define KITERS (DIM / BK)   // 16
#define TPE    3         // m-tiles per expert (validated: max expert count <= 384)
#define LROW   72        // shorts per LDS row: 64 bf16 + 8 pad = 144 B (16B-mult)
#define TSZ    (MT * LROW)
#define NXCD   8
#define EPX    (NSESS / NXCD)        // experts per XCD = 4
#define BPE    (TPE * (DIM / NTILE)) // blocks per expert = 24

typedef __attribute__((ext_vector_type(8))) short short8;
typedef __attribute__((ext_vector_type(4))) float floatx4;
typedef __attribute__((ext_vector_type(4))) int intx4;
typedef __attribute__((ext_vector_type(2))) unsigned int uintx2;

// RNE fp32->bf16 for two values, packed into one dword via v_perm_b32.
__device__ __forceinline__ unsigned pack_bf16_2(float fa, float fb) {
  unsigned a = __builtin_bit_cast(unsigned, fa);
  unsigned b = __builtin_bit_cast(unsigned, fb);
  a += 0x7fffu + ((a >> 16) & 1u);
  b += 0x7fffu + ((b >> 16) & 1u);
  return __builtin_amdgcn_perm(b, a, 0x07060302u); // low = bf16(fa), high = bf16(fb)
}

// Round-8 structure (post-mortem r7: launch_bounds(256,4) capped the unified
// file at 128 regs/wave vs ~192 live -> ~64-reg spill catastrophe, WRITE_SIZE
// 39->100MB, FETCH +105MB scratch; occupancy DID double, so TLP mechanism is
// untested, not refuted). This round: register diet to fit 3 waves/SIMD
// (budget 512/3 ~= 168) WITHOUT spills:
//  - 32-bit byte-offset arrays (aoff/boff) + uniform SGPR base -> saddr-form
//    global_load; kb*256B folds into the 13-bit imm. -16 VGPR, -16 addr adds.
//  - COMPUTE streams fa one-at-a-time against resident fb[4]: frag peak -12.
//  - __launch_bounds__(256,3): 3 blocks/CU (LDS 38.4KB would allow 4; regs cap 3).
//  - keep: r6 single-buffer loop (131us), XCD-clustered remap, 16Bx16-lane row
//    staging, bf16 LDS +16B pad, k0 B-loads before the sidx scan.
// Spill canary: WRITE_SIZE must stay ~39MB (output-only).
__global__ __launch_bounds__(256, 3) void gemm_kernel(
    const float* __restrict__ x, const float* __restrict__ W,
    const float* __restrict__ bias, const int* __restrict__ sidx,
    float* __restrict__ out)
{
  __shared__ __align__(16) short As[TSZ], Bs[TSZ];
  __shared__ int row_ids[MT];
  __shared__ int psum[256];

  // ---- XCD-clustered decode ----
  const int hw    = blockIdx.x;          // 0..767, assumed XCD = hw % 8
  const int xcd   = hw & (NXCD - 1);
  const int r     = hw >> 3;             // 0..95: within-XCD sequence
  const int s     = xcd * EPX + (r / BPE);   // expert, clustered per XCD
  const int rr    = r % BPE;             // 0..23
  const int ntile = rr / TPE;            // 0..7 (W slice shared by 3 mtiles)
  const int mtile = rr % TPE;
  const int tid   = threadIdx.x;

  const int lane = tid & 63;
  const int wv   = tid >> 6;            // wave id
  const int wm   = wv >> 1;             // 0..1 : 64-row half
  const int wn   = wv & 1;              // 0..1 : 64-col half
  const int fr   = lane & 15;           // fragment row within 16
  const int kg   = lane >> 4;           // fragment k-group (k = kg*8 + j)

  // ---- staging geometry: instr j covers tile-rows srow+j*4, 256 B each ----
  const int srow   = wv * 32 + (lane >> 4);
  const int schunk = lane & 15;

  // B byte-offsets + k0 B-loads issued immediately (hide under the sidx scan).
  unsigned boff[8];
  floatx4 wreg[8];
  {
    const unsigned wbyte =
        (unsigned)(((size_t)s * DIM * DIM + (size_t)(ntile * NTILE) * DIM) * 4u);
#pragma unroll
    for (int j = 0; j < 8; ++j) {
      const int tr = srow + j * 4;
      boff[j] = wbyte + (unsigned)((tr * DIM + schunk * 4) * 4);
      wreg[j] = *(const floatx4*)((const char*)W + boff[j]);
    }
  }

  // ---- ranked compaction: rows with sidx==s, ranks [mtile*128, +128) ----
  const intx4* sv = (const intx4*)(sidx + tid * 32);
  int c = 0;
#pragma unroll
  for (int j = 0; j < 8; ++j) {
    const intx4 v = sv[j];
#pragma unroll
    for (int e = 0; e < 4; ++e) c += (v[e] == s);
  }
  psum[tid] = c;
  __syncthreads();
#pragma unroll
  for (int d = 1; d < 256; d <<= 1) {
    const int mine = psum[tid];
    const int add  = (tid >= d) ? psum[tid - d] : 0;
    __syncthreads();
    psum[tid] = mine + add;
    __syncthreads();
  }
  const int total = psum[255];
  const int nrows = (total - mtile * MT) < 0 ? 0
                  : ((total - mtile * MT) > MT ? MT : (total - mtile * MT));
  if (nrows == 0) return;               // uniform across block
  const int base_rank = psum[tid] - c;

  if (tid < MT) row_ids[tid] = -1;
  __syncthreads();
  {
    int r2 = base_rank;
    const int lo = mtile * MT, hi = lo + MT;
#pragma unroll
    for (int j = 0; j < 8; ++j) {
      const intx4 v = sv[j];
#pragma unroll
      for (int e = 0; e < 4; ++e) {
        if (v[e] == s) {
          if (r2 >= lo && r2 < hi) row_ids[r2 - lo] = tid * 32 + 4 * j + e;
          ++r2;
        }
      }
    }
  }
  __syncthreads();

  unsigned aoff[8];
  floatx4 xreg[8];
#pragma unroll
  for (int j = 0; j < 8; ++j) {
    int ar = row_ids[srow + j * 4];
    if (ar < 0) ar = 0;                 // finite dummy; epilogue masks rows >= nrows
    aoff[j] = (unsigned)((ar * DIM + schunk * 4) * 4);
    xreg[j] = *(const floatx4*)((const char*)x + aoff[j]);  // k0 A-loads
  }

  floatx4 acc[4][4] = {};

#define LOADREGS(KB)                                                           \
  {                                                                            \
    _Pragma("unroll")                                                          \
    for (int j = 0; j < 8; ++j) {                                              \
      xreg[j] = *(const floatx4*)((const char*)x + aoff[j] + (KB) * (BK * 4)); \
      wreg[j] = *(const floatx4*)((const char*)W + boff[j] + (KB) * (BK * 4)); \
    }                                                                          \
  }

#define CVTWRITE()                                                             \
  {                                                                            \
    _Pragma("unroll")                                                          \
    for (int j = 0; j < 8; ++j) {                                              \
      const int off = (srow + j * 4) * LROW + schunk * 4;                      \
      uintx2 ua = { pack_bf16_2(xreg[j][0], xreg[j][1]),                       \
                    pack_bf16_2(xreg[j][2], xreg[j][3]) };                     \
      uintx2 ub = { pack_bf16_2(wreg[j][0], wreg[j][1]),                       \
                    pack_bf16_2(wreg[j][2], wreg[j][3]) };                     \
      *(uintx2*)&As[off] = ua;                                                 \
      *(uintx2*)&Bs[off] = ub;                                                 \
    }                                                                          \
  }

#define COMPUTE()                                                              \
  {                                                                            \
    _Pragma("unroll")                                                          \
    for (int s2 = 0; s2 < 2; ++s2) {                                           \
      short8 fb[4];                                                            \
      _Pragma("unroll")                                                        \
      for (int i = 0; i < 4; ++i)                                              \
        fb[i] = *(const short8*)&Bs[(wn * 64 + i * 16 + fr) * LROW + s2 * 32 + kg * 8]; \
      _Pragma("unroll")                                                        \
      for (int mi = 0; mi < 4; ++mi) {                                         \
        const short8 fa = *(const short8*)&As[(wm * 64 + mi * 16 + fr) * LROW + s2 * 32 + kg * 8]; \
        _Pragma("unroll")                                                      \
        for (int ni = 0; ni < 4; ++ni)                                         \
          acc[mi][ni] = __builtin_amdgcn_mfma_f32_16x16x32_bf16(               \
              fa, fb[ni], acc[mi][ni], 0, 0, 0);                               \
      }                                                                        \
    }                                                                          \
  }

  // prologue: k0 already in regs -> stage into LDS
  CVTWRITE();
  __syncthreads();

  for (int kb = 0; kb < KITERS; ++kb) {
    if (kb + 1 < KITERS) LOADREGS(kb + 1);   // in flight across compute+barrier
    COMPUTE();
    if (kb + 1 < KITERS) {
      __syncthreads();                       // all waves done reading LDS
      CVTWRITE();                            // vmcnt wait lands here
      __syncthreads();                       // writes visible
    }
  }

#undef LOADREGS
#undef CVTWRITE
#undef COMPUTE

  // epilogue: D row = (lane>>4)*4 + reg, D col = lane&15
  const int col0 = ntile * NTILE + wn * 64;
#pragma unroll
  for (int ni = 0; ni < 4; ++ni) {
    const int n = col0 + ni * 16 + fr;
    const float bv = bias[s * DIM + n];
#pragma unroll
    for (int mi = 0; mi < 4; ++mi) {
      const int mbase = wm * 64 + mi * 16 + kg * 4;
#pragma unroll
      for (int rr2 = 0; rr2 < 4; ++rr2) {
        const int ml = mbase + rr2;
        if (ml < nrows) {
          const int orow = row_ids[ml];
          out[(size_t)orow * DIM + n] = acc[mi][ni][rr2] + bv;
        }
      }
    }
  }
}

extern "C" void kernel_launch(void* const* d_in, const int* in_sizes, int n_in,
                              void* d_out, int out_size, void* d_ws, size_t ws_size,
                              hipStream_t stream) {
  const float* x    = (const float*)d_in[0];
  const float* W    = (const float*)d_in[1];
  const float* b    = (const float*)d_in[2];
  const int*   sidx = (const int*)d_in[3];
  float* out = (float*)d_out;
  (void)d_ws; (void)ws_size;  // deliberately unused (round-1 post-mortem)

  hipLaunchKernelGGL(gemm_kernel, dim3(NSESS * TPE * (DIM / NTILE)), dim3(256), 0, stream,
                     x, W, b, sidx, out);
}